// Round 10
// baseline (255.896 us; speedup 1.0000x reference)
//
#include <hip/hip_runtime.h>
#include <hip/hip_fp16.h>
#include <cstdint>
#include <cstddef>

#define H    50
#define TT   256      // timesteps
#define BATCH 512
#define KDIM 144      // layer-0 input dim
#define ODIM 144      // FC output dim
#define NW   32       // windows
#define WS   8        // steps per window

typedef _Float16 half8  __attribute__((ext_vector_type(8)));
typedef _Float16 half4v __attribute__((ext_vector_type(4)));
typedef float    floatx4 __attribute__((ext_vector_type(4)));
typedef int      int4v  __attribute__((ext_vector_type(4)));

__device__ __forceinline__ float rcpf(float x) { return __builtin_amdgcn_rcpf(x); }
__device__ __forceinline__ float sigm(float x) { return rcpf(1.0f + __expf(-x)); }
__device__ __forceinline__ float tanhx(float x) {
    return 1.0f - 2.0f * rcpf(__expf(2.0f * x) + 1.0f);
}

// Raw barrier: orders LDS (lgkmcnt) but leaves global loads (vmcnt) in flight.
__device__ __forceinline__ void sync_lds() {
    asm volatile("s_waitcnt lgkmcnt(0)\n\ts_barrier" ::: "memory");
}
// Wave-local LDS write->read ordering (once per window after gp scatter).
__device__ __forceinline__ void wave_lds_fence() {
    asm volatile("s_waitcnt lgkmcnt(0)" ::: "memory");
}

// ---------- A-fragment builders (A layout: row m = lane&15, k = q*8 + j) ----------
// K=64 hidden rows (Whh0 / Whh1): k<50 = W[p][k], else 0.
__device__ __forceinline__ half8 make_hh(const float* __restrict__ Wt,
                                         int kkA, int gate, int q, int s) {
    const float* r0 = Wt + (size_t)(gate * H + (kkA < H ? kkA : 0)) * H;
    half8 r;
    #pragma unroll
    for (int j = 0; j < 8; ++j) {
        const int k = s * 32 + q * 8 + j;
        r[j] = (_Float16)((kkA < H && k < H) ? r0[k] : 0.0f);
    }
    return r;
}
// x-projection rows: K=160 pad; k<144 = W_ih0, k==144 = bias0 (rides 1.0 B-channel)
__device__ __forceinline__ half8 make_ax(const float* __restrict__ Wih0,
                                         const float* __restrict__ bih0,
                                         const float* __restrict__ bhh0,
                                         int kkA, int gate, int q, int s) {
    const int p = gate * H + (kkA < H ? kkA : 0);
    half8 r;
    #pragma unroll
    for (int j = 0; j < 8; ++j) {
        const int k = s * 32 + q * 8 + j;
        float v = 0.0f;
        if (kkA < H) {
            if (k < KDIM)        v = Wih0[(size_t)p * KDIM + k];
            else if (k == KDIM)  v = bih0[p] + bhh0[p];
        }
        r[j] = (_Float16)v;
    }
    return r;
}
// L1 input-projection rows (over h0 window): K=64; k<50 = W_ih1, k==50 = bias1.
__device__ __forceinline__ half8 make_p1(const float* __restrict__ Wih1,
                                         const float* __restrict__ bih1,
                                         const float* __restrict__ bhh1,
                                         int kkA, int gate, int q, int s) {
    const int p = gate * H + (kkA < H ? kkA : 0);
    half8 r;
    #pragma unroll
    for (int j = 0; j < 8; ++j) {
        const int k = s * 32 + q * 8 + j;
        float v = 0.0f;
        if (kkA < H) {
            if (k < H)           v = Wih1[(size_t)p * H + k];
            else if (k == H)     v = bih1[p] + bhh1[p];
        }
        r[j] = (_Float16)v;
    }
    return r;
}

// ---------- Fused kernel: R9 base (broadcast-B cndmask select, no setprio, 1 raw
// barrier/step) + R4's windowed L1: per step only hh MFMAs (a0 2-dep K64 over h0,
// a1 2-dep K64 over h1) = 8/wave. L1's input part Wih1*h0+b1 is batched per 8-step
// window (gp1) from the HW h0-window buffer; L0 x-proj batched per window (gp0).
// L1 lags L0 by one full window; tail window finishes L1, then fused FC. ----------
__global__ __launch_bounds__(512, 1) void lstm_fused(
    const float* __restrict__ X,
    const float* __restrict__ Whh0, const float* __restrict__ Wih0,
    const float* __restrict__ bih0, const float* __restrict__ bhh0,
    const float* __restrict__ Wih1, const float* __restrict__ Whh1,
    const float* __restrict__ bih1, const float* __restrict__ bhh1,
    const float* __restrict__ Wfc, const float* __restrict__ bfc,
    float* __restrict__ out)
{
    const int b0   = blockIdx.x * 2;
    const int tid  = threadIdx.x;
    const int lane = tid & 63;
    const int w    = tid >> 6;       // wave 0..7
    const int col  = lane & 15;      // C col
    const int q    = lane >> 4;      // 0..3

    __shared__ __align__(16) _Float16 B0[2][2][4][2][8];    // h0 state [buf][s][q][r][j], K=64
    __shared__ __align__(16) _Float16 B1[2][2][4][2][8];    // h1 state
    __shared__ __align__(16) _Float16 HW[2][2][4][16][8];   // h0 window [wbuf][s][q][2t+r][j], 1.0@k=50
    __shared__ __align__(16) float    gp0[64 * 72];         // L0 xproj quads [u][t*8+r*4+g]
    __shared__ __align__(16) float    gp1[64 * 72];         // L1 h0proj quads
    __shared__ __align__(16) _Float16 XB[2][5][4][16][8];   // x B-frags [buf][s][q][2t+r][j], 1.0@k=144
    __shared__ float h1f[2][52];

    // ---- inline A-prep: 22 frags (2 tiles x {hh0:2, ax:5, hh1:2, p1:2}) ----
    int4v Ap[22];
    {
        const int prow = lane & 15;
        const int gate = prow & 3;
        const int kkA0 = 8 * w + 0 + (prow >> 2);
        const int kkA1 = 8 * w + 4 + (prow >> 2);
        Ap[0] = __builtin_bit_cast(int4v, make_hh(Whh0, kkA0, gate, q, 0));
        Ap[1] = __builtin_bit_cast(int4v, make_hh(Whh0, kkA0, gate, q, 1));
        Ap[2] = __builtin_bit_cast(int4v, make_hh(Whh0, kkA1, gate, q, 0));
        Ap[3] = __builtin_bit_cast(int4v, make_hh(Whh0, kkA1, gate, q, 1));
        #pragma unroll
        for (int s = 0; s < 5; ++s) Ap[4 + s] = __builtin_bit_cast(int4v, make_ax(Wih0, bih0, bhh0, kkA0, gate, q, s));
        #pragma unroll
        for (int s = 0; s < 5; ++s) Ap[9 + s] = __builtin_bit_cast(int4v, make_ax(Wih0, bih0, bhh0, kkA1, gate, q, s));
        Ap[14] = __builtin_bit_cast(int4v, make_hh(Whh1, kkA0, gate, q, 0));
        Ap[15] = __builtin_bit_cast(int4v, make_hh(Whh1, kkA0, gate, q, 1));
        Ap[16] = __builtin_bit_cast(int4v, make_hh(Whh1, kkA1, gate, q, 0));
        Ap[17] = __builtin_bit_cast(int4v, make_hh(Whh1, kkA1, gate, q, 1));
        Ap[18] = __builtin_bit_cast(int4v, make_p1(Wih1, bih1, bhh1, kkA0, gate, q, 0));
        Ap[19] = __builtin_bit_cast(int4v, make_p1(Wih1, bih1, bhh1, kkA0, gate, q, 1));
        Ap[20] = __builtin_bit_cast(int4v, make_p1(Wih1, bih1, bhh1, kkA1, gate, q, 0));
        Ap[21] = __builtin_bit_cast(int4v, make_p1(Wih1, bih1, bhh1, kkA1, gate, q, 1));
    }
    #pragma unroll
    for (int i = 0; i < 22; ++i) asm volatile("" : "+a"(Ap[i]));

    // ---- act decode: lane (col,q) owns cell (unit au, layer aL, row r) ----
    const int  c2m  = (col >> 1) & 3;    // quad select (cols 8..15 duplicate, masked)
    const int  r    = col & 1;           // batch row
    const int  atl  = c2m & 1;           // tile
    const int  aL   = c2m >> 1;          // layer
    const int  au   = 8 * w + 4 * atl + q;
    const bool valid = (col < 8);
    const bool areal = (au < H);
    float c = 0.0f;
    const float* gpb = (aL ? gp1 : gp0) + au * 72;

    // ---- x-stage decode: 576 float4/window over 512(+64) threads ----
    const int cs1 = tid / 36,         kk1 = tid % 36;
    const int cs2 = (tid + 512) / 36, kk2 = (tid + 512) % 36;
    const float* xp1 = X + ((size_t)(b0 + (cs1 & 1)) * TT + (cs1 >> 1)) * KDIM + kk1 * 4;
    const float* xp2 = X + ((size_t)(b0 + (cs2 & 1)) * TT + (cs2 >> 1)) * KDIM + kk2 * 4;

    // ---- init: zero B0/B1/HW/XB, set 1.0 channels, stage XB[0] ----
    if (tid < 128) { ((int*)B0)[tid] = 0; ((int*)B1)[tid] = 0; }
    for (int i = tid; i < 1024; i += 512) ((int*)HW)[i] = 0;
    for (int i = tid; i < 2560; i += 512) ((int*)XB)[i] = 0;
    __syncthreads();
    if (tid < 32) {
        HW[tid >> 4][1][2][tid & 15][2] = (_Float16)1.0f;  // k=50 bias1 channel
        XB[tid >> 4][4][2][tid & 15][0] = (_Float16)1.0f;  // k=144 bias0 channel
    }
    {
        const float4 v1 = *(const float4*)xp1;
        const int s = kk1 >> 3, qq = (kk1 >> 1) & 3, j0 = (kk1 & 1) * 4;
        half4v h; h[0]=(_Float16)v1.x; h[1]=(_Float16)v1.y; h[2]=(_Float16)v1.z; h[3]=(_Float16)v1.w;
        *(half4v*)&XB[0][s][qq][cs1][j0] = h;
        if (tid < 64) {
            const float4 v2 = *(const float4*)xp2;
            const int s2 = kk2 >> 3, q2 = (kk2 >> 1) & 3, j2 = (kk2 & 1) * 4;
            half4v h2; h2[0]=(_Float16)v2.x; h2[1]=(_Float16)v2.y; h2[2]=(_Float16)v2.z; h2[3]=(_Float16)v2.w;
            *(half4v*)&XB[0][s2][q2][cs2][j2] = h2;
        }
    }
    __syncthreads();

    const int gb = (col >> 1) * 8 + (col & 1) * 4;   // proj scatter offset (t*8 + r*4)

    for (int W = 0; W < NW; ++W) {
        #pragma unroll
        for (int i = 0; i < 22; ++i) asm volatile("" : "+a"(Ap[i]));
        const int cb = W & 1, nb = cb ^ 1, pb = cb ^ 1;
        const bool more = (W + 1) < NW;
        // issue next-window x loads (consumed at step 3 -> latency hidden)
        float4 xv1, xv2;
        if (more) {
            xv1 = *(const float4*)(xp1 + (size_t)(W + 1) * WS * KDIM);
            if (tid < 64) xv2 = *(const float4*)(xp2 + (size_t)(W + 1) * WS * KDIM);
        }
        // ---- window top: L0 x-proj + bias0 for 16 tokens (8t x 2r) ----
        {
            half8 xbf[5];
            #pragma unroll
            for (int s = 0; s < 5; ++s) xbf[s] = *(const half8*)&XB[cb][s][q][col][0];
            floatx4 px0 = (floatx4)(0.0f), px1 = (floatx4)(0.0f);
            #pragma unroll
            for (int s = 0; s < 5; ++s) {
                px0 = __builtin_amdgcn_mfma_f32_16x16x32_f16(__builtin_bit_cast(half8, Ap[4 + s]), xbf[s], px0, 0, 0, 0);
                px1 = __builtin_amdgcn_mfma_f32_16x16x32_f16(__builtin_bit_cast(half8, Ap[9 + s]), xbf[s], px1, 0, 0, 0);
            }
            *(floatx4*)&gp0[(8 * w + q) * 72 + gb]     = px0;
            *(floatx4*)&gp0[(8 * w + 4 + q) * 72 + gb] = px1;
        }
        // ---- window top: L1 h0-proj + bias1 over previous window's h0 (HW[pb]) ----
        if (W > 0) {
            half8 hbf[2];
            #pragma unroll
            for (int s = 0; s < 2; ++s) hbf[s] = *(const half8*)&HW[pb][s][q][col][0];
            floatx4 pw0 = (floatx4)(0.0f), pw1 = (floatx4)(0.0f);
            #pragma unroll
            for (int s = 0; s < 2; ++s) {
                pw0 = __builtin_amdgcn_mfma_f32_16x16x32_f16(__builtin_bit_cast(half8, Ap[18 + s]), hbf[s], pw0, 0, 0, 0);
                pw1 = __builtin_amdgcn_mfma_f32_16x16x32_f16(__builtin_bit_cast(half8, Ap[20 + s]), hbf[s], pw1, 0, 0, 0);
            }
            *(floatx4*)&gp1[(8 * w + q) * 72 + gb]     = pw0;
            *(floatx4*)&gp1[(8 * w + 4 + q) * 72 + gb] = pw1;
        }
        wave_lds_fence();   // gp scatter -> same-wave act reads
        // ---- 8 serial steps: L0 at t=8W+i, L1 at t'=8(W-1)+i ----
        #pragma unroll
        for (int i = 0; i < WS; ++i) {
            const int rb = i & 1, wb = rb ^ 1;
            half8 bf0[2], bf1[2];
            #pragma unroll
            for (int s = 0; s < 2; ++s) {
                bf0[s] = *(const half8*)&B0[rb][s][q][r][0];   // broadcast read
                bf1[s] = *(const half8*)&B1[rb][s][q][r][0];
            }
            const floatx4 gx = *(const floatx4*)&gpb[i * 8 + r * 4];
            floatx4 a0[2], a1[2];
            #pragma unroll
            for (int tl = 0; tl < 2; ++tl) { a0[tl] = (floatx4)(0.0f); a1[tl] = (floatx4)(0.0f); }
            #pragma unroll
            for (int tl = 0; tl < 2; ++tl) {
                #pragma unroll
                for (int s = 0; s < 2; ++s) {
                    a0[tl] = __builtin_amdgcn_mfma_f32_16x16x32_f16(__builtin_bit_cast(half8, Ap[tl*2+s]),    bf0[s], a0[tl], 0, 0, 0);
                    a1[tl] = __builtin_amdgcn_mfma_f32_16x16x32_f16(__builtin_bit_cast(half8, Ap[14+tl*2+s]), bf1[s], a1[tl], 0, 0, 0);
                }
            }
            // ---- in-register quad select (8 cndmask) ----
            floatx4 g;
            #pragma unroll
            for (int gi_ = 0; gi_ < 4; ++gi_) {
                const float s01 = (c2m & 1) ? a0[1][gi_] : a0[0][gi_];
                const float s23 = (c2m & 1) ? a1[1][gi_] : a1[0][gi_];
                g[gi_] = (c2m & 2) ? s23 : s01;
            }
            g[0] += gx[0]; g[1] += gx[1]; g[2] += gx[2]; g[3] += gx[3];
            // ---- act: one cell per lane (L1 lags a window: dead at W==0) ----
            const float gi = sigm(g[0]), gf = sigm(g[1]);
            const float gg = tanhx(g[2]), go = sigm(g[3]);
            const bool en = (aL == 0) || (W > 0);
            const float cn = gf * c + gi * gg;
            c = en ? cn : c;
            const float hv = go * tanhx(c);
            if (valid && areal && en) {
                const _Float16 h16 = (_Float16)hv;
                if (aL == 0) {
                    B0[wb][au >> 5][(au >> 3) & 3][r][au & 7] = h16;
                    HW[cb][au >> 5][(au >> 3) & 3][2 * i + r][au & 7] = h16;
                } else {
                    B1[wb][au >> 5][(au >> 3) & 3][r][au & 7] = h16;
                }
            }
            // mid-window: write next-window x into XB[nb] (loads long in flight)
            if (i == 3 && more) {
                {
                    const int s = kk1 >> 3, qq = (kk1 >> 1) & 3, j0 = (kk1 & 1) * 4;
                    half4v h; h[0]=(_Float16)xv1.x; h[1]=(_Float16)xv1.y; h[2]=(_Float16)xv1.z; h[3]=(_Float16)xv1.w;
                    *(half4v*)&XB[nb][s][qq][cs1][j0] = h;
                }
                if (tid < 64) {
                    const int s2 = kk2 >> 3, q2 = (kk2 >> 1) & 3, j2 = (kk2 & 1) * 4;
                    half4v h2; h2[0]=(_Float16)xv2.x; h2[1]=(_Float16)xv2.y; h2[2]=(_Float16)xv2.z; h2[3]=(_Float16)xv2.w;
                    *(half4v*)&XB[nb][s2][q2][cs2][j2] = h2;
                }
            }
            sync_lds();         // B0/B1[wb], HW[cb], XB[nb] -> next step
        }
    }
    // ---- tail window: L1 for t' = TT-8 .. TT-1 (h0 from HW[(NW-1)&1]) ----
    {
        #pragma unroll
        for (int i = 0; i < 22; ++i) asm volatile("" : "+a"(Ap[i]));
        {
            half8 hbf[2];
            #pragma unroll
            for (int s = 0; s < 2; ++s) hbf[s] = *(const half8*)&HW[(NW - 1) & 1][s][q][col][0];
            floatx4 pw0 = (floatx4)(0.0f), pw1 = (floatx4)(0.0f);
            #pragma unroll
            for (int s = 0; s < 2; ++s) {
                pw0 = __builtin_amdgcn_mfma_f32_16x16x32_f16(__builtin_bit_cast(half8, Ap[18 + s]), hbf[s], pw0, 0, 0, 0);
                pw1 = __builtin_amdgcn_mfma_f32_16x16x32_f16(__builtin_bit_cast(half8, Ap[20 + s]), hbf[s], pw1, 0, 0, 0);
            }
            *(floatx4*)&gp1[(8 * w + q) * 72 + gb]     = pw0;
            *(floatx4*)&gp1[(8 * w + 4 + q) * 72 + gb] = pw1;
        }
        wave_lds_fence();
        #pragma unroll
        for (int i = 0; i < WS; ++i) {
            const int rb = i & 1, wb = rb ^ 1;
            half8 bf1[2];
            #pragma unroll
            for (int s = 0; s < 2; ++s) bf1[s] = *(const half8*)&B1[rb][s][q][r][0];
            const floatx4 gx = *(const floatx4*)&gpb[i * 8 + r * 4];
            floatx4 a1[2];
            #pragma unroll
            for (int tl = 0; tl < 2; ++tl) {
                a1[tl] = (floatx4)(0.0f);
                #pragma unroll
                for (int s = 0; s < 2; ++s)
                    a1[tl] = __builtin_amdgcn_mfma_f32_16x16x32_f16(__builtin_bit_cast(half8, Ap[14+tl*2+s]), bf1[s], a1[tl], 0, 0, 0);
            }
            floatx4 g;
            #pragma unroll
            for (int gi_ = 0; gi_ < 4; ++gi_)
                g[gi_] = (c2m & 1) ? a1[1][gi_] : a1[0][gi_];
            g[0] += gx[0]; g[1] += gx[1]; g[2] += gx[2]; g[3] += gx[3];
            const float gi = sigm(g[0]), gf = sigm(g[1]);
            const float gg = tanhx(g[2]), go = sigm(g[3]);
            const bool en = (aL == 1);
            const float cn = gf * c + gi * gg;
            c = en ? cn : c;
            const float hv = go * tanhx(c);
            if (valid && en && areal) {
                B1[wb][au >> 5][(au >> 3) & 3][r][au & 7] = (_Float16)hv;
                if (i == WS - 1) h1f[r][au] = hv;
            }
            sync_lds();
        }
    }
    // ---- fused FC on h1(TT-1): 2 rows x 144 outs ----
    if (tid < 2 * ODIM) {
        const int rr = tid / ODIM, o = tid - rr * ODIM;
        float s = bfc[o];
        const float* wr = Wfc + (size_t)o * H;
        #pragma unroll
        for (int k = 0; k < H; ++k) s += wr[k] * h1f[rr][k];
        out[(size_t)(b0 + rr) * ODIM + o] = s;
    }
}

extern "C" void kernel_launch(void* const* d_in, const int* in_sizes, int n_in,
                              void* d_out, int out_size, void* d_ws, size_t ws_size,
                              hipStream_t stream) {
    const float* x    = (const float*)d_in[0];
    const float* wih0 = (const float*)d_in[1];
    const float* whh0 = (const float*)d_in[2];
    const float* bih0 = (const float*)d_in[3];
    const float* bhh0 = (const float*)d_in[4];
    const float* wih1 = (const float*)d_in[5];
    const float* whh1 = (const float*)d_in[6];
    const float* bih1 = (const float*)d_in[7];
    const float* bhh1 = (const float*)d_in[8];
    const float* wfc  = (const float*)d_in[9];
    const float* bfc  = (const float*)d_in[10];
    float* outp = (float*)d_out;

    lstm_fused<<<BATCH / 2, 512, 0, stream>>>(x, whh0, wih0, bih0, bhh0,
                                              wih1, whh1, bih1, bhh1,
                                              wfc, bfc, outp);
}